// Round 2
// baseline (4348.118 us; speedup 1.0000x reference)
//
#include <hip/hip_runtime.h>
#include <cstdint>
#include <cstddef>

// Bidirectional LSTM  B=32 T=1024 D=512 H=256 (torch gate order i,f,g,o), fp32 in/out.
//
// Phase 1 (per batch-chunk): xp[m][n] = sum_k x16[m][k] * W16[n][k] + bias[n]
//   fp16 MFMA GEMM, K=512, xp stored fp16.  m = b_local*T + t, n = dir*1024 + gate_row.
// Phase 2 (per batch-chunk): persistent recurrent kernel, blocks = 4 slices x 2 dirs x nbg
//   batch-pairs. Whh rows live in VGPRs (packed fp16). h exchanged between the 4 slice
//   blocks of a (dir,batchpair) group via d_out + agent-scope atomics + per-step flags
//   (flags zeroed by hipMemsetAsync before each lstm launch -> deterministic in graphs).
// Chunk count c in {1,2,4,8,16} chosen from ws_size: need(c) ~= 160MB/c + 2MB.

typedef unsigned int   uint;
typedef unsigned short ushort;

constexpr int Tn = 1024;
constexpr int Bn = 32;
constexpr int Dn = 512;
constexpr int Hn = 256;
constexpr int NC = 2048;          // 2 dirs * 4H
constexpr int KT = 512;           // K of the input projection (fp16, no compensation)

typedef _Float16 half8  __attribute__((ext_vector_type(8)));
typedef _Float16 half2v __attribute__((ext_vector_type(2)));
typedef float    f32x4  __attribute__((ext_vector_type(4)));

#if defined(__has_builtin)
#  if __has_builtin(__builtin_amdgcn_fdot2)
#    define HAVE_FDOT2 1
#  endif
#endif

__device__ __forceinline__ ushort f2h(float f) {
  _Float16 h = (_Float16)f;               // RNE
  return __builtin_bit_cast(ushort, h);
}
__device__ __forceinline__ float h2f(ushort s) {
  return (float)__builtin_bit_cast(_Float16, s);
}

// packed-fp16 dual MAC: acc += w.lo*h.lo + w.hi*h.hi  (v_dot2_f32_f16)
__device__ __forceinline__ float dot2h(uint w, uint h, float acc) {
#ifdef HAVE_FDOT2
  return __builtin_amdgcn_fdot2(__builtin_bit_cast(half2v, w),
                                __builtin_bit_cast(half2v, h), acc, false);
#else
  acc = fmaf(h2f((ushort)(w & 0xffff)), h2f((ushort)(h & 0xffff)), acc);
  acc = fmaf(h2f((ushort)(w >> 16)),    h2f((ushort)(h >> 16)),    acc);
  return acc;
#endif
}

__device__ __forceinline__ float sig_(float x) {
  x = fminf(fmaxf(x, -30.f), 30.f);
  return 1.f / (1.f + __expf(-x));
}
__device__ __forceinline__ float tanh_(float x) {
  x = fminf(fmaxf(x, -15.f), 15.f);
  float e = __expf(2.f * x);
  return (e - 1.f) / (e + 1.f);
}

// ---------------- prep kernels ----------------

// x (chunk) fp32 -> fp16, 4 elements/thread
__global__ void k_prep_a(const float* __restrict__ x, ushort* __restrict__ a16, long nquad) {
  long i4 = (long)blockIdx.x * blockDim.x + threadIdx.x;
  if (i4 >= nquad) return;
  const float4 v = ((const float4*)x)[i4];
  ushort4 o;
  o.x = f2h(v.x); o.y = f2h(v.y); o.z = f2h(v.z); o.w = f2h(v.w);
  ((ushort4*)a16)[i4] = o;
}

// W16 [2048][512] fp16 (rows: dir*1024+g), biasc[n] = bih[g]+bhh[g] per dir
__global__ void k_prep_w(const float* __restrict__ wf, const float* __restrict__ wb,
                         const float* __restrict__ bf1, const float* __restrict__ bf2,
                         const float* __restrict__ bb1, const float* __restrict__ bb2,
                         ushort* __restrict__ w16, float* __restrict__ biasc) {
  long i4 = (long)blockIdx.x * blockDim.x + threadIdx.x;
  if (i4 >= (long)NC * (KT / 4)) return;
  int n = (int)(i4 >> 7);              // /128 quads per row
  int k4 = (int)(i4 & 127);
  int dir = n >> 10, g = n & 1023;
  const float* w = dir ? wb : wf;
  const float4 v = ((const float4*)(w + (size_t)g * Dn))[k4];
  ushort4 o;
  o.x = f2h(v.x); o.y = f2h(v.y); o.z = f2h(v.z); o.w = f2h(v.w);
  ((ushort4*)w16)[i4] = o;
  if (k4 == 0) biasc[n] = dir ? (bb1[g] + bb2[g]) : (bf1[g] + bf2[g]);
}

__global__ void k_bad(float* __restrict__ out, int n) {
  int i = blockIdx.x * blockDim.x + threadIdx.x;
  if (i < n) out[i] = 54321.f;   // sentinel: ws_size too small for every config
}

// ---------------- phase 1: fp16 MFMA GEMM ----------------
// BM=BN=128, BK=32, 4 waves 2x2, 16 K-iterations.

__device__ __forceinline__ void gload_lds16(const void* g, void* l) {
  __builtin_amdgcn_global_load_lds((const __attribute__((address_space(1))) void*)g,
                                   (__attribute__((address_space(3))) void*)l, 16, 0, 0);
}

__global__ __launch_bounds__(256) void k_gemm(const ushort* __restrict__ A,
                                              const ushort* __restrict__ W,
                                              const float* __restrict__ biasc,
                                              ushort* __restrict__ xp) {
  __shared__ __align__(16) ushort As[128 * 32];
  __shared__ __align__(16) ushort Bs[128 * 32];
  const int bid = blockIdx.x;
  const int m0 = (bid >> 4) * 128;
  const int n0 = (bid & 15) * 128;
  const int tid = threadIdx.x;
  const int wid = tid >> 6, lane = tid & 63;
  const int wr = wid >> 1, wcq = wid & 1;
  const int l16 = lane & 15, lq = lane >> 4;

  f32x4 acc[4][4] = {};

  for (int kt = 0; kt < KT; kt += 32) {
    __syncthreads();
    // stage 8KB A + 8KB B. granule (16B) XOR-swizzle: source granule gs = gp ^ ((r>>1)&3)
    // stored at linear LDS granule gp -> ds_read conflict reduced to 2-way (free).
#pragma unroll
    for (int i = 0; i < 2; ++i) {
      int ch = wid * 2 + i;
      int p = ch * 64 + lane;
      int r = p >> 2, gp = p & 3;
      int gs = gp ^ ((r >> 1) & 3);
      gload_lds16(A + (size_t)(m0 + r) * KT + kt + gs * 8, (char*)As + ch * 1024);
      gload_lds16(W + (size_t)(n0 + r) * KT + kt + gs * 8, (char*)Bs + ch * 1024);
    }
    __syncthreads();

    half8 af[4], bfr[4];
#pragma unroll
    for (int mf = 0; mf < 4; ++mf) {
      int row = wr * 64 + mf * 16 + l16;
      int g = lq ^ ((row >> 1) & 3);
      af[mf] = *(const half8*)((const char*)As + row * 64 + g * 16);
    }
#pragma unroll
    for (int nf = 0; nf < 4; ++nf) {
      int row = wcq * 64 + nf * 16 + l16;
      int g = lq ^ ((row >> 1) & 3);
      bfr[nf] = *(const half8*)((const char*)Bs + row * 64 + g * 16);
    }
#pragma unroll
    for (int mf = 0; mf < 4; ++mf)
#pragma unroll
      for (int nf = 0; nf < 4; ++nf)
        acc[mf][nf] = __builtin_amdgcn_mfma_f32_16x16x32_f16(af[mf], bfr[nf], acc[mf][nf], 0, 0, 0);
  }

#pragma unroll
  for (int nf = 0; nf < 4; ++nf) {
    int col = n0 + wcq * 64 + nf * 16 + l16;
    float bv = biasc[col];
#pragma unroll
    for (int mf = 0; mf < 4; ++mf) {
      int rbase = m0 + wr * 64 + mf * 16 + lq * 4;
#pragma unroll
      for (int i = 0; i < 4; ++i)
        xp[(size_t)(rbase + i) * NC + col] = f2h(acc[mf][nf][i] + bv);
    }
  }
}

// ---------------- phase 2: persistent recurrence ----------------
// bid = slice*(2*nbg) + grp, grp = dir*nbg + bg. Block owns gate rows
// R = g4*256 + slice*64 + j for batches (b0, b0+1); Whh row in 128 packed-fp16 VGPRs.

__global__ __launch_bounds__(256, 1) void k_lstm(const float* __restrict__ whhF,
                                                 const float* __restrict__ whhB,
                                                 const ushort* __restrict__ xp,
                                                 float* __restrict__ out,
                                                 int* __restrict__ flags,
                                                 int b_base, int nbg) {
  const int bid = blockIdx.x;
  const int grp = bid % (2 * nbg);
  const int slice = bid / (2 * nbg);
  const int dir = grp / nbg;
  const int bg = grp % nbg;
  const int b0 = bg * 2;                      // chunk-local batch
  const int tid = threadIdx.x;
  const int g4 = tid >> 6;
  const int j = tid & 63;
  const int R = g4 * Hn + slice * 64 + j;     // gate row 0..1023

  __shared__ __align__(16) uint hp[2][128];   // packed fp16 h, [batch][k/2]
  __shared__ float gbuf[4][2][64];
  ushort* hpu = (ushort*)hp;

  const float* whh = dir ? whhB : whhF;

  // persistent weights: row R of Whh [1024][256] -> 128 packed-fp16 VGPRs
  uint wreg[128];
  {
    const float2* wr2 = (const float2*)(whh + (size_t)R * Hn);
#pragma unroll
    for (int q = 0; q < 128; ++q) {
      float2 w = wr2[q];
      wreg[q] = (uint)f2h(w.x) | ((uint)f2h(w.y) << 16);
    }
  }

  ((uint*)hp)[tid] = 0;     // h_{-1} = 0
  float creg = 0.f;         // c for (batch tid>>6, out tid&63) on threads 0..127
  __syncthreads();

  const int dstep = dir ? -1 : 1;
  int tphys = dir ? (Tn - 1) : 0;
  const ptrdiff_t xstride = (ptrdiff_t)dstep * NC;
  const ushort* pxp0 = xp + (size_t)(b0 * Tn + tphys) * NC + dir * 1024 + R;
  const ushort* pxp1 = pxp0 + (size_t)Tn * NC;
  ushort xq0 = *pxp0, xq1 = *pxp1;

  for (int t = 0; t < Tn; ++t) {
    float a0 = h2f(xq0), a1 = h2f(xq1);
    if (t + 1 < Tn) { pxp0 += xstride; pxp1 += xstride; xq0 = *pxp0; xq1 = *pxp1; }

    const uint4* h40 = (const uint4*)&hp[0][0];
    const uint4* h41 = (const uint4*)&hp[1][0];
#pragma unroll
    for (int q = 0; q < 32; ++q) {
      uint4 hA = h40[q], hB = h41[q];
      a0 = dot2h(wreg[4 * q + 0], hA.x, a0);
      a1 = dot2h(wreg[4 * q + 0], hB.x, a1);
      a0 = dot2h(wreg[4 * q + 1], hA.y, a0);
      a1 = dot2h(wreg[4 * q + 1], hB.y, a1);
      a0 = dot2h(wreg[4 * q + 2], hA.z, a0);
      a1 = dot2h(wreg[4 * q + 2], hB.z, a1);
      a0 = dot2h(wreg[4 * q + 3], hA.w, a0);
      a1 = dot2h(wreg[4 * q + 3], hB.w, a1);
    }
    gbuf[g4][0][j] = a0;
    gbuf[g4][1][j] = a1;
    __syncthreads();

    if (tid < 128) {
      const int ab = tid >> 6, aj = tid & 63;
      float gi = gbuf[0][ab][aj], gf = gbuf[1][ab][aj];
      float gg = gbuf[2][ab][aj], go = gbuf[3][ab][aj];
      float iv = sig_(gi), fv = sig_(gf), gv = tanh_(gg), ov = sig_(go);
      float c = fv * creg + iv * gv;
      creg = c;
      float h = ov * tanh_(c);
      float* po = out + (size_t)((b_base + b0 + ab) * Tn + tphys) * 512 + dir * 256 + slice * 64 + aj;
      __hip_atomic_store(po, h, __ATOMIC_RELAXED, __HIP_MEMORY_SCOPE_AGENT);
      hpu[ab * 256 + slice * 64 + aj] = f2h(h);
    }
    // drain own stores before anyone publishes the flag
    asm volatile("s_waitcnt vmcnt(0)" ::: "memory");
    __syncthreads();
    if (tid == 0)
      __hip_atomic_store(&flags[bid], t + 1, __ATOMIC_RELAXED, __HIP_MEMORY_SCOPE_AGENT);
    if (tid < 3) {
      const int sp = (slice + 1 + tid) & 3;
      const int* pf = &flags[sp * (2 * nbg) + grp];
      while (__hip_atomic_load(pf, __ATOMIC_RELAXED, __HIP_MEMORY_SCOPE_AGENT) <= t) {}
    }
    __syncthreads();
    if (tid < 192) {
      const int pc = tid >> 6, pj = tid & 63;
      const int sp = (slice + 1 + pc) & 3;
      const float* ps0 = out + (size_t)((b_base + b0) * Tn + tphys) * 512 + dir * 256 + sp * 64 + pj;
      float v0 = __hip_atomic_load(ps0, __ATOMIC_RELAXED, __HIP_MEMORY_SCOPE_AGENT);
      float v1 = __hip_atomic_load(ps0 + (size_t)Tn * 512, __ATOMIC_RELAXED, __HIP_MEMORY_SCOPE_AGENT);
      hpu[sp * 64 + pj] = f2h(v0);
      hpu[256 + sp * 64 + pj] = f2h(v1);
    }
    __syncthreads();
    tphys += dstep;
  }
}

// ---------------- host ----------------

extern "C" void kernel_launch(void* const* d_in, const int* in_sizes, int n_in,
                              void* d_out, int out_size, void* d_ws, size_t ws_size,
                              hipStream_t stream) {
  const float* x     = (const float*)d_in[0];
  const float* Wih_f = (const float*)d_in[1];
  const float* Whh_f = (const float*)d_in[2];
  const float* bih_f = (const float*)d_in[3];
  const float* bhh_f = (const float*)d_in[4];
  const float* Wih_b = (const float*)d_in[5];
  const float* Whh_b = (const float*)d_in[6];
  const float* bib_b = (const float*)d_in[7];
  const float* bhh_b = (const float*)d_in[8];
  float* out = (float*)d_out;

  const size_t szW16  = (size_t)NC * KT * 2;        // 2 MiB
  const size_t szBias = (size_t)NC * 4;             // 8 KiB
  const size_t szFl   = 512;

  // pick smallest chunk count whose footprint fits ws_size
  int c = 0;
  size_t szA16 = 0, szXp = 0;
  for (int cc = 1; cc <= 16; cc *= 2) {
    size_t a = (size_t)(Bn / cc) * Tn * KT * 2;     // x fp16, chunk
    size_t p = (size_t)(Bn / cc) * Tn * NC * 2;     // xp fp16, chunk
    if (szW16 + szBias + a + p + szFl <= ws_size) { c = cc; szA16 = a; szXp = p; break; }
  }
  if (c == 0) {
    k_bad<<<(out_size + 255) / 256, 256, 0, stream>>>(out, out_size);
    return;
  }

  char* ws = (char*)d_ws;
  ushort* W16   = (ushort*)ws;
  float*  biasc = (float*)(ws + szW16);
  ushort* A16   = (ushort*)(ws + szW16 + szBias);
  ushort* xp    = (ushort*)(ws + szW16 + szBias + szA16);
  int*    flags = (int*)(ws + szW16 + szBias + szA16 + szXp);

  {
    long n4 = (long)NC * (KT / 4);
    k_prep_w<<<(int)((n4 + 255) / 256), 256, 0, stream>>>(Wih_f, Wih_b, bih_f, bhh_f,
                                                          bib_b, bhh_b, W16, biasc);
  }

  const int sizeB = Bn / c;          // batches per chunk (>= 2)
  const int nbg = sizeB / 2;         // batch-pairs per chunk
  for (int cb = 0; cb < c; ++cb) {
    const int b_base = cb * sizeB;
    {
      long nquad = (long)sizeB * Tn * KT / 4;
      k_prep_a<<<(int)((nquad + 255) / 256), 256, 0, stream>>>(
          x + (size_t)b_base * Tn * Dn, A16, nquad);
    }
    k_gemm<<<dim3(sizeB * 8 * 16), dim3(256), 0, stream>>>(A16, W16, biasc, xp);
    hipMemsetAsync(flags, 0, szFl, stream);
    k_lstm<<<dim3(4 * 2 * nbg), dim3(256), 0, stream>>>(Whh_f, Whh_b, xp, out, flags,
                                                        b_base, nbg);
  }
}

// Round 3
// 2058.520 us; speedup vs baseline: 2.1123x; 2.1123x over previous
//
#include <hip/hip_runtime.h>
#include <cstdint>
#include <cstddef>

// Bidirectional LSTM  B=32 T=1024 D=512 H=256 (torch gate order i,f,g,o), fp32 in/out.
//
// Phase 1 (per batch-chunk): xp[m][n] = sum_k x16[m][k] * W16[n][k] + bias[n]
//   fp16 MFMA GEMM, K=512, xp stored fp16.  m = b_local*T + t, n = dir*1024 + gate_row.
// Phase 2: ONE block per (dir, batch) chain -> zero cross-block communication.
//   1024 threads, thread tid owns gate row tid. Whh row (256 fp16 = 128 packed words):
//   98 words in VGPRs + 30 words in LDS (q-major). h broadcast via LDS (512 B).
//   Per step: 128 v_dot2_f32_f16 + 2 __syncthreads.

typedef unsigned int   uint;
typedef unsigned short ushort;

constexpr int Tn = 1024;
constexpr int Bn = 32;
constexpr int Dn = 512;
constexpr int Hn = 256;
constexpr int NC = 2048;          // 2 dirs * 4H
constexpr int KT = 512;           // K of the input projection

typedef _Float16 half8  __attribute__((ext_vector_type(8)));
typedef _Float16 half2v __attribute__((ext_vector_type(2)));
typedef float    f32x4  __attribute__((ext_vector_type(4)));

#if defined(__has_builtin)
#  if __has_builtin(__builtin_amdgcn_fdot2)
#    define HAVE_FDOT2 1
#  endif
#endif

__device__ __forceinline__ ushort f2h(float f) {
  _Float16 h = (_Float16)f;               // RNE
  return __builtin_bit_cast(ushort, h);
}
__device__ __forceinline__ float h2f(ushort s) {
  return (float)__builtin_bit_cast(_Float16, s);
}
__device__ __forceinline__ uint packh(float a, float b) {
  return (uint)f2h(a) | ((uint)f2h(b) << 16);
}

// packed-fp16 dual MAC: acc += w.lo*h.lo + w.hi*h.hi  (v_dot2_f32_f16)
__device__ __forceinline__ float dot2h(uint w, uint h, float acc) {
#ifdef HAVE_FDOT2
  return __builtin_amdgcn_fdot2(__builtin_bit_cast(half2v, w),
                                __builtin_bit_cast(half2v, h), acc, false);
#else
  acc = fmaf(h2f((ushort)(w & 0xffff)), h2f((ushort)(h & 0xffff)), acc);
  acc = fmaf(h2f((ushort)(w >> 16)),    h2f((ushort)(h >> 16)),    acc);
  return acc;
#endif
}

__device__ __forceinline__ float sig_(float x) {
  x = fminf(fmaxf(x, -30.f), 30.f);
  return 1.f / (1.f + __expf(-x));
}
__device__ __forceinline__ float tanh_(float x) {
  x = fminf(fmaxf(x, -15.f), 15.f);
  float e = __expf(2.f * x);
  return (e - 1.f) / (e + 1.f);
}

// ---------------- prep kernels ----------------

__global__ void k_prep_a(const float* __restrict__ x, ushort* __restrict__ a16, long nquad) {
  long i4 = (long)blockIdx.x * blockDim.x + threadIdx.x;
  if (i4 >= nquad) return;
  const float4 v = ((const float4*)x)[i4];
  ushort4 o;
  o.x = f2h(v.x); o.y = f2h(v.y); o.z = f2h(v.z); o.w = f2h(v.w);
  ((ushort4*)a16)[i4] = o;
}

__global__ void k_prep_w(const float* __restrict__ wf, const float* __restrict__ wb,
                         const float* __restrict__ bf1, const float* __restrict__ bf2,
                         const float* __restrict__ bb1, const float* __restrict__ bb2,
                         ushort* __restrict__ w16, float* __restrict__ biasc) {
  long i4 = (long)blockIdx.x * blockDim.x + threadIdx.x;
  if (i4 >= (long)NC * (KT / 4)) return;
  int n = (int)(i4 >> 7);
  int k4 = (int)(i4 & 127);
  int dir = n >> 10, g = n & 1023;
  const float* w = dir ? wb : wf;
  const float4 v = ((const float4*)(w + (size_t)g * Dn))[k4];
  ushort4 o;
  o.x = f2h(v.x); o.y = f2h(v.y); o.z = f2h(v.z); o.w = f2h(v.w);
  ((ushort4*)w16)[i4] = o;
  if (k4 == 0) biasc[n] = dir ? (bb1[g] + bb2[g]) : (bf1[g] + bf2[g]);
}

__global__ void k_bad(float* __restrict__ out, int n) {
  int i = blockIdx.x * blockDim.x + threadIdx.x;
  if (i < n) out[i] = 54321.f;
}

// ---------------- phase 1: fp16 MFMA GEMM ----------------

__device__ __forceinline__ void gload_lds16(const void* g, void* l) {
  __builtin_amdgcn_global_load_lds((const __attribute__((address_space(1))) void*)g,
                                   (__attribute__((address_space(3))) void*)l, 16, 0, 0);
}

__global__ __launch_bounds__(256) void k_gemm(const ushort* __restrict__ A,
                                              const ushort* __restrict__ W,
                                              const float* __restrict__ biasc,
                                              ushort* __restrict__ xp) {
  __shared__ __align__(16) ushort As[128 * 32];
  __shared__ __align__(16) ushort Bs[128 * 32];
  const int bid = blockIdx.x;
  const int m0 = (bid >> 4) * 128;
  const int n0 = (bid & 15) * 128;
  const int tid = threadIdx.x;
  const int wid = tid >> 6, lane = tid & 63;
  const int wr = wid >> 1, wcq = wid & 1;
  const int l16 = lane & 15, lq = lane >> 4;

  f32x4 acc[4][4] = {};

  for (int kt = 0; kt < KT; kt += 32) {
    __syncthreads();
#pragma unroll
    for (int i = 0; i < 2; ++i) {
      int ch = wid * 2 + i;
      int p = ch * 64 + lane;
      int r = p >> 2, gp = p & 3;
      int gs = gp ^ ((r >> 1) & 3);
      gload_lds16(A + (size_t)(m0 + r) * KT + kt + gs * 8, (char*)As + ch * 1024);
      gload_lds16(W + (size_t)(n0 + r) * KT + kt + gs * 8, (char*)Bs + ch * 1024);
    }
    __syncthreads();

    half8 af[4], bfr[4];
#pragma unroll
    for (int mf = 0; mf < 4; ++mf) {
      int row = wr * 64 + mf * 16 + l16;
      int g = lq ^ ((row >> 1) & 3);
      af[mf] = *(const half8*)((const char*)As + row * 64 + g * 16);
    }
#pragma unroll
    for (int nf = 0; nf < 4; ++nf) {
      int row = wcq * 64 + nf * 16 + l16;
      int g = lq ^ ((row >> 1) & 3);
      bfr[nf] = *(const half8*)((const char*)Bs + row * 64 + g * 16);
    }
#pragma unroll
    for (int mf = 0; mf < 4; ++mf)
#pragma unroll
      for (int nf = 0; nf < 4; ++nf)
        acc[mf][nf] = __builtin_amdgcn_mfma_f32_16x16x32_f16(af[mf], bfr[nf], acc[mf][nf], 0, 0, 0);
  }

#pragma unroll
  for (int nf = 0; nf < 4; ++nf) {
    int col = n0 + wcq * 64 + nf * 16 + l16;
    float bv = biasc[col];
#pragma unroll
    for (int mf = 0; mf < 4; ++mf) {
      int rbase = m0 + wr * 64 + mf * 16 + lq * 4;
#pragma unroll
      for (int i = 0; i < 4; ++i)
        xp[(size_t)(rbase + i) * NC + col] = f2h(acc[mf][nf][i] + bv);
    }
  }
}

// ---------------- phase 2: one block per (dir, batch) chain ----------------
// grid = 2*sizeB blocks of 1024 threads. blockIdx: dir = &1, batch_local = >>1.
// LDS: wl4[7][1024] uint4 (k=200..255) + wl2[1024] uint2 (k=196..199) + gates + h.
// VGPR: wreg[98] (k=0..195).  Total LDS = 114688+8192+2048+512 = 125440 B.

constexpr int WREG = 98;

__global__ __launch_bounds__(1024, 4) void k_lstm(const float* __restrict__ whhF,
                                                  const float* __restrict__ whhB,
                                                  const ushort* __restrict__ xp,
                                                  float* __restrict__ out,
                                                  int b_base) {
  const int dir = blockIdx.x & 1;
  const int bl  = blockIdx.x >> 1;
  const int tid = threadIdx.x;                 // gate row 0..1023

  __shared__ __align__(16) uint4 wl4[7][1024];
  __shared__ __align__(16) uint2 wl2[1024];
  __shared__ ushort gb16[1024];
  __shared__ __align__(16) uint hp32[128];     // packed fp16 h[256]

  const float* whh = dir ? whhB : whhF;

  uint wreg[WREG];
  {
    const float4* wr4 = (const float4*)(whh + (size_t)tid * Hn);
#pragma unroll
    for (int i = 0; i < 49; ++i) {
      float4 v = wr4[i];
      wreg[2 * i]     = packh(v.x, v.y);
      wreg[2 * i + 1] = packh(v.z, v.w);
    }
    float4 v = wr4[49];                        // k = 196..199
    wl2[tid] = (uint2){ packh(v.x, v.y), packh(v.z, v.w) };
#pragma unroll
    for (int q = 0; q < 7; ++q) {              // k = 200+8q .. 207+8q
      float4 a = wr4[50 + 2 * q], b = wr4[51 + 2 * q];
      wl4[q][tid] = (uint4){ packh(a.x, a.y), packh(a.z, a.w),
                             packh(b.x, b.y), packh(b.z, b.w) };
    }
  }
  if (tid < 128) hp32[tid] = 0;                // h_{-1} = 0
  float creg = 0.f;                            // c for output (tid) on threads 0..255
  __syncthreads();

  const int dstep = dir ? -1 : 1;
  int tphys = dir ? (Tn - 1) : 0;
  const ptrdiff_t xstr = (ptrdiff_t)dstep * NC;
  const ptrdiff_t ostr = (ptrdiff_t)dstep * 512;
  const ushort* pxp = xp + (size_t)(bl * Tn + tphys) * NC + dir * 1024 + tid;
  float* pout = out + (size_t)((b_base + bl) * Tn + tphys) * 512 + dir * 256 + (tid & 255);
  ushort xq = *pxp;

  const uint4* hp4 = (const uint4*)hp32;

  for (int t = 0; t < Tn; ++t) {
    float a = h2f(xq);
    if (t + 1 < Tn) { pxp += xstr; xq = *pxp; }

#pragma unroll
    for (int q = 0; q < 24; ++q) {             // k = 0..191 (VGPR weights)
      uint4 h4 = hp4[q];
      a = dot2h(wreg[4 * q + 0], h4.x, a);
      a = dot2h(wreg[4 * q + 1], h4.y, a);
      a = dot2h(wreg[4 * q + 2], h4.z, a);
      a = dot2h(wreg[4 * q + 3], h4.w, a);
    }
    {                                          // k = 192..199 (reg tail + wl2)
      uint4 h4 = hp4[24];
      a = dot2h(wreg[96], h4.x, a);
      a = dot2h(wreg[97], h4.y, a);
      uint2 w2 = wl2[tid];
      a = dot2h(w2.x, h4.z, a);
      a = dot2h(w2.y, h4.w, a);
    }
#pragma unroll
    for (int q = 0; q < 7; ++q) {              // k = 200..255 (LDS weights)
      uint4 w4 = wl4[q][tid];
      uint4 h4 = hp4[25 + q];
      a = dot2h(w4.x, h4.x, a);
      a = dot2h(w4.y, h4.y, a);
      a = dot2h(w4.z, h4.z, a);
      a = dot2h(w4.w, h4.w, a);
    }
    gb16[tid] = f2h(a);
    __syncthreads();

    if (tid < 256) {
      float gi = h2f(gb16[tid]);
      float gf = h2f(gb16[tid + 256]);
      float gg = h2f(gb16[tid + 512]);
      float go = h2f(gb16[tid + 768]);
      float c = sig_(gf) * creg + sig_(gi) * tanh_(gg);
      creg = c;
      float h = sig_(go) * tanh_(c);
      *pout = h;
      ((ushort*)hp32)[tid] = f2h(h);
    }
    pout += ostr;
    __syncthreads();
    tphys += dstep;
  }
}

// ---------------- host ----------------

extern "C" void kernel_launch(void* const* d_in, const int* in_sizes, int n_in,
                              void* d_out, int out_size, void* d_ws, size_t ws_size,
                              hipStream_t stream) {
  const float* x     = (const float*)d_in[0];
  const float* Wih_f = (const float*)d_in[1];
  const float* Whh_f = (const float*)d_in[2];
  const float* bih_f = (const float*)d_in[3];
  const float* bhh_f = (const float*)d_in[4];
  const float* Wih_b = (const float*)d_in[5];
  const float* Whh_b = (const float*)d_in[6];
  const float* bib_b = (const float*)d_in[7];
  const float* bhh_b = (const float*)d_in[8];
  float* out = (float*)d_out;

  const size_t szW16  = (size_t)NC * KT * 2;        // 2 MiB
  const size_t szBias = (size_t)NC * 4;

  int c = 0;
  size_t szA16 = 0, szXp = 0;
  for (int cc = 1; cc <= 16; cc *= 2) {
    size_t a = (size_t)(Bn / cc) * Tn * KT * 2;
    size_t p = (size_t)(Bn / cc) * Tn * NC * 2;
    if (szW16 + szBias + a + p <= ws_size) { c = cc; szA16 = a; szXp = p; break; }
  }
  if (c == 0) {
    k_bad<<<(out_size + 255) / 256, 256, 0, stream>>>(out, out_size);
    return;
  }

  char* ws = (char*)d_ws;
  ushort* W16   = (ushort*)ws;
  float*  biasc = (float*)(ws + szW16);
  ushort* A16   = (ushort*)(ws + szW16 + szBias);
  ushort* xp    = (ushort*)(ws + szW16 + szBias + szA16);

  {
    long n4 = (long)NC * (KT / 4);
    k_prep_w<<<(int)((n4 + 255) / 256), 256, 0, stream>>>(Wih_f, Wih_b, bih_f, bhh_f,
                                                          bib_b, bhh_b, W16, biasc);
  }

  const int sizeB = Bn / c;
  for (int cb = 0; cb < c; ++cb) {
    const int b_base = cb * sizeB;
    {
      long nquad = (long)sizeB * Tn * KT / 4;
      k_prep_a<<<(int)((nquad + 255) / 256), 256, 0, stream>>>(
          x + (size_t)b_base * Tn * Dn, A16, nquad);
    }
    k_gemm<<<dim3(sizeB * 8 * 16), dim3(256), 0, stream>>>(A16, W16, biasc, xp);
    k_lstm<<<dim3(2 * sizeB), dim3(1024), 0, stream>>>(Whh_f, Whh_b, xp, out, b_base);
  }
}